// Round 2
// baseline (128.604 us; speedup 1.0000x reference)
//
#include <hip/hip_runtime.h>
#include <math.h>

// Problem constants (from reference): B=2048, I=512, O=512
#define B_DIM 2048
#define I_DIM 512
#define O_DIM 512

constexpr int R_ROWS  = 16;              // b-rows per block
constexpr int T_O     = 4;               // o's per thread (the new lever: 4x VALU per LDS read)
constexpr int LANES   = 64;              // threadIdx.x = one wave
constexpr int W_CHUNK = 8;               // i-chunks (threadIdx.y), 64 i each
constexpr int O_BLK   = LANES * T_O;     // 256 o per block
constexpr int CHUNK   = I_DIM / W_CHUNK; // 64 i per chunk
constexpr int QPT     = CHUNK / 4;       // 16 i-quads per thread

// ---------------------------------------------------------------------------
// Setup kernel: precompute the affine ab table.
//   factor[b,i,o] = 1 - w*(1 - xnor) = a[i,o] + bcoef[i,o]*x[b,i]
//   a = 1 - w*s ; bcoef = w*(2s - 1)
// ab layout: float4 (a0,a1,b0,b1) at ab4[k*O_DIM+o], k = i/2.
// ---------------------------------------------------------------------------
__global__ __launch_bounds__(256) void setup_kernel(
    const float* __restrict__ w_logits,
    const float* __restrict__ s_logits,
    float4* __restrict__ ab4)
{
    int t  = blockIdx.x * 256 + threadIdx.x;  // 0 .. 131071
    int o  = t & (O_DIM - 1);
    int k  = t >> 9;                          // i-pair index, 0..255
    int i0 = 2 * k;

    float zw0 = w_logits[(i0 + 0) * O_DIM + o];
    float zs0 = s_logits[(i0 + 0) * O_DIM + o];
    float zw1 = w_logits[(i0 + 1) * O_DIM + o];
    float zs1 = s_logits[(i0 + 1) * O_DIM + o];

    float w0 = 1.0f / (1.0f + expf(-zw0));
    float s0 = 1.0f / (1.0f + expf(-zs0));
    float w1 = 1.0f / (1.0f + expf(-zw1));
    float s1 = 1.0f / (1.0f + expf(-zs1));

    float4 v;
    v.x = fmaf(-w0, s0, 1.0f);        // a0
    v.y = fmaf(-w1, s1, 1.0f);        // a1
    v.z = w0 * (2.0f * s0 - 1.0f);    // b0
    v.w = w1 * (2.0f * s1 - 1.0f);    // b1
    ab4[k * O_DIM + o] = v;
}

// ---------------------------------------------------------------------------
// Main product kernel. Block (64,8) = 512 threads = 8 waves. Each thread:
// 16 b-rows x 4 o's x 64 i. Lanes span o (coalesced ab loads, 4 segments of
// 64 o each); threadIdx.y = i-chunk. Grid (2,128) = 256 blocks = 1/CU.
//
// R1 post-mortem: the per-(row,quad) broadcast ds_read_b128 was the wall
// (16 waves x 512 reads x ~12 cyc = 98k cyc/CU ~= the measured 44us; VALU
// floor is only 33k cyc). T_O=4 reuses every x-quad LDS read for 4 outputs:
// VALU:LDS goes 8:1 -> 32:1, LDS pipe drops to ~75% of the VALU time and
// VALU (13.7us floor) becomes the bound.
// ---------------------------------------------------------------------------
__global__ __launch_bounds__(512, 2) void fuzzy_main(
    const float* __restrict__ x,       // (B, I) fp32
    const float4* __restrict__ ab4,
    float* __restrict__ out)
{
    // 64 KB LDS, overlaid: x-tile (32 KB) during the product loop, then the
    // 4-buffer combine region (64 KB) after a barrier.
    __shared__ __align__(16) unsigned char sh_raw[4 * R_ROWS * O_BLK * 4];
    float4 (*xs4)[I_DIM / 4] =
        reinterpret_cast<float4(*)[I_DIM / 4]>(sh_raw);                    // [16][128]
    float (*part)[R_ROWS][O_BLK] =
        reinterpret_cast<float(*)[R_ROWS][O_BLK]>(sh_raw);                 // [4][16][256]

    const int lane  = threadIdx.x;                                   // 0..63
    const int y     = __builtin_amdgcn_readfirstlane((int)threadIdx.y); // 0..7, wave-uniform
    const int tid   = y * LANES + lane;                              // 0..511
    const int obase = blockIdx.x * O_BLK;
    const int g     = blockIdx.y;                                    // b-group (16 rows)
    const int b0    = g * R_ROWS;
    const int qbase = y * QPT;                                       // first global i-quad

    // Lane-varying base + uniform offsets -> saddr-form global loads.
    const float4* abp = ab4 + obase + lane;

    // Prime the 2-deep ab pipeline: set A = quad qbase, set B = quad qbase+1.
    // Each quad needs pair-rows 2q (i=4q,4q+1) and 2q+1 (i=4q+2,4q+3) for
    // all 4 o-segments.
    float4 cA0[T_O], cA1[T_O], cB0[T_O], cB1[T_O];
#pragma unroll
    for (int j = 0; j < T_O; ++j) {
        cA0[j] = abp[(size_t)(2 * qbase + 0) * O_DIM + 64 * j];
        cA1[j] = abp[(size_t)(2 * qbase + 1) * O_DIM + 64 * j];
        cB0[j] = abp[(size_t)(2 * qbase + 2) * O_DIM + 64 * j];
        cB1[j] = abp[(size_t)(2 * qbase + 3) * O_DIM + 64 * j];
    }

    // Stage x tile: 16 rows x 512 f = 2048 float4; 512 threads x 4, coalesced.
    {
        const float4* x4 = (const float4*)x;
#pragma unroll
        for (int p = 0; p < 4; ++p) {
            int fidx = p * 512 + tid;             // 0..2047
            int r = fidx >> 7;                    // row 0..15
            int q = fidx & 127;                   // quad 0..127
            xs4[r][q] = x4[(size_t)(b0 + r) * (I_DIM / 4) + q];
        }
    }
    __syncthreads();

    float acc[R_ROWS][T_O];
#pragma unroll
    for (int r = 0; r < R_ROWS; ++r)
#pragma unroll
        for (int j = 0; j < T_O; ++j) acc[r][j] = 1.0f;

    for (int qq = 0; qq < QPT; qq += 2) {
        // ---- body A: quad qbase+qq ----
        {
            const int q = qbase + qq;
            float4 xv[R_ROWS];
#pragma unroll
            for (int r = 0; r < R_ROWS; ++r) xv[r] = xs4[r][q];  // broadcast ds_read_b128
#pragma unroll
            for (int r = 0; r < R_ROWS; ++r) {
#pragma unroll
                for (int j = 0; j < T_O; ++j) {
                    float f0 = fmaf(cA0[j].z, xv[r].x, cA0[j].x);
                    float f1 = fmaf(cA0[j].w, xv[r].y, cA0[j].y);
                    float f2 = fmaf(cA1[j].z, xv[r].z, cA1[j].x);
                    float f3 = fmaf(cA1[j].w, xv[r].w, cA1[j].y);
                    acc[r][j] *= (f0 * f2) * (f1 * f3);
                }
            }
            // Refill set A with quad q+2 (covered by body B's compute).
            // Final iters overrun ab4 by <=4 rows (32 KB) -> inside ws slack.
#pragma unroll
            for (int j = 0; j < T_O; ++j) {
                cA0[j] = abp[(size_t)(2 * q + 4) * O_DIM + 64 * j];
                cA1[j] = abp[(size_t)(2 * q + 5) * O_DIM + 64 * j];
            }
        }
        // ---- body B: quad qbase+qq+1 ----
        {
            const int q = qbase + qq + 1;
            float4 xv[R_ROWS];
#pragma unroll
            for (int r = 0; r < R_ROWS; ++r) xv[r] = xs4[r][q];
#pragma unroll
            for (int r = 0; r < R_ROWS; ++r) {
#pragma unroll
                for (int j = 0; j < T_O; ++j) {
                    float f0 = fmaf(cB0[j].z, xv[r].x, cB0[j].x);
                    float f1 = fmaf(cB0[j].w, xv[r].y, cB0[j].y);
                    float f2 = fmaf(cB1[j].z, xv[r].z, cB1[j].x);
                    float f3 = fmaf(cB1[j].w, xv[r].w, cB1[j].y);
                    acc[r][j] *= (f0 * f2) * (f1 * f3);
                }
            }
#pragma unroll
            for (int j = 0; j < T_O; ++j) {
                cB0[j] = abp[(size_t)(2 * q + 4) * O_DIM + 64 * j];
                cB1[j] = abp[(size_t)(2 * q + 5) * O_DIM + 64 * j];
            }
        }
    }

    // ---- combine the 8 i-chunk partials per (row, o) ----
    // Phase 1: chunks 0..3 write their partials (overlays xs4 -> barrier 1st).
    __syncthreads();
    if (y < 4) {
#pragma unroll
        for (int r = 0; r < R_ROWS; ++r)
#pragma unroll
            for (int j = 0; j < T_O; ++j)
                part[y][r][64 * j + lane] = acc[r][j];
    }
    __syncthreads();
    // Phase 2: chunks 4..7 multiply into buffers 0..3 (1:1, race-free).
    if (y >= 4) {
#pragma unroll
        for (int r = 0; r < R_ROWS; ++r)
#pragma unroll
            for (int j = 0; j < T_O; ++j)
                part[y - 4][r][64 * j + lane] *= acc[r][j];
    }
    __syncthreads();
    // Phase 3: fold the 4 buffers; 4096 outputs / 512 threads = 8 each,
    // lane-consecutive columns -> coalesced stores.
#pragma unroll
    for (int p = 0; p < 8; ++p) {
        int idx = p * 512 + tid;                  // 0..4095
        int r = idx >> 8;                         // 0..15
        int c = idx & (O_BLK - 1);                // 0..255
        float v = part[0][r][c] * part[1][r][c]
                * part[2][r][c] * part[3][r][c];
        out[(size_t)(b0 + r) * O_DIM + obase + c] = v;
    }
}

extern "C" void kernel_launch(void* const* d_in, const int* in_sizes, int n_in,
                              void* d_out, int out_size, void* d_ws, size_t ws_size,
                              hipStream_t stream) {
    const float* x        = (const float*)d_in[0];   // (B, I) fp32
    const float* w_logits = (const float*)d_in[1];   // (I, O) fp32
    const float* s_logits = (const float*)d_in[2];   // (I, O) fp32
    float* out = (float*)d_out;                      // (B, O) fp32
    float4* ab4 = (float4*)d_ws;                     // [0, 2MB) + prefetch slack

    // Setup: ab table only (512 blocks).
    setup_kernel<<<dim3(512), dim3(256), 0, stream>>>(w_logits, s_logits, ab4);

    // Grid (O/256, B/16) = (2, 128) = 256 blocks of (64,8)=512 threads.
    fuzzy_main<<<dim3(O_DIM / O_BLK, B_DIM / R_ROWS), dim3(LANES, W_CHUNK), 0, stream>>>(
        x, ab4, out);
}

// Round 3
// 92.046 us; speedup vs baseline: 1.3972x; 1.3972x over previous
//
#include <hip/hip_runtime.h>
#include <math.h>

// Problem constants (from reference): B=2048, I=512, O=512
#define B_DIM 2048
#define I_DIM 512
#define O_DIM 512

constexpr int LANES   = 64;                    // threadIdx.x = one wave, spans 64 o
constexpr int T_O     = 4;                     // o's per thread (VALU:LDS = 28:1 read)
constexpr int O_BLK   = LANES * T_O;           // 256 o per block
constexpr int NCHUNK  = 4;                     // i-chunks (128 i each)
constexpr int NHALF   = 2;                     // row halves
constexpr int R_BLOCK = 16;                    // rows per block (keeps ab L2 demand ~35 B/cy/CU)
constexpr int R_HALF  = R_BLOCK / NHALF;       // 8 rows per thread (halves acc VGPRs vs R2)
constexpr int QPC     = (I_DIM / 4) / NCHUNK;  // 32 i-quads per chunk

// ---------------------------------------------------------------------------
// Setup kernel: precompute the affine ab table.
//   factor[b,i,o] = 1 - w*(1 - xnor) = a[i,o] + bcoef[i,o]*x[b,i]
//   a = 1 - w*s ; bcoef = w*(2s - 1)
// ab layout: float4 (a0,a1,b0,b1) at ab4[k*O_DIM+o], k = i/2.
// ---------------------------------------------------------------------------
__global__ __launch_bounds__(256) void setup_kernel(
    const float* __restrict__ w_logits,
    const float* __restrict__ s_logits,
    float4* __restrict__ ab4)
{
    int t  = blockIdx.x * 256 + threadIdx.x;  // 0 .. 131071
    int o  = t & (O_DIM - 1);
    int k  = t >> 9;                          // i-pair index, 0..255
    int i0 = 2 * k;

    float zw0 = w_logits[(i0 + 0) * O_DIM + o];
    float zs0 = s_logits[(i0 + 0) * O_DIM + o];
    float zw1 = w_logits[(i0 + 1) * O_DIM + o];
    float zs1 = s_logits[(i0 + 1) * O_DIM + o];

    float w0 = 1.0f / (1.0f + expf(-zw0));
    float s0 = 1.0f / (1.0f + expf(-zs0));
    float w1 = 1.0f / (1.0f + expf(-zw1));
    float s1 = 1.0f / (1.0f + expf(-zs1));

    float4 v;
    v.x = fmaf(-w0, s0, 1.0f);        // a0
    v.y = fmaf(-w1, s1, 1.0f);        // a1
    v.z = w0 * (2.0f * s0 - 1.0f);    // b0
    v.w = w1 * (2.0f * s1 - 1.0f);    // b1
    ab4[k * O_DIM + o] = v;
}

// ---------------------------------------------------------------------------
// Main product kernel. Block (64,8) = 8 waves: threadIdx.y = (half<<2)|chunk.
// Each thread: 8 b-rows x 4 o x 128 i. Grid (2,128) = 256 blocks = 1/CU.
//
// R2 post-mortem: R=16 x T_O=4 + xv[16] demanded ~280 VGPRs -> scratch spill
// (WRITE_SIZE 197 MB, VALUBusy 21%). This version keeps 16 rows per BLOCK
// (per-block ab slice is 1 MB regardless of R, so 1 block/CU keeps ab L2
// demand at ~35 B/cy/CU) but splits rows across 2 wave-groups: acc drops to
// 8x4=32 VGPRs, xv is per-row transient. Est. ~130 VGPRs -> no spill.
// Per-CU model: VALU 28.7k cyc (12.0us) vs LDS broadcast 24.6k cyc (10.2us).
// ---------------------------------------------------------------------------
__global__ __launch_bounds__(512, 2) void fuzzy_main(
    const float* __restrict__ x,       // (B, I) fp32
    const float4* __restrict__ ab4,
    float* __restrict__ out)
{
    // 64 KB LDS, overlaid: x-tile (32 KB) during the product loop, then the
    // 4-chunk combine buffer (64 KB) after a barrier.
    __shared__ __align__(16) unsigned char sh_raw[NCHUNK * R_BLOCK * O_BLK * 4];
    float4 (*xs4)[I_DIM / 4] =
        reinterpret_cast<float4(*)[I_DIM / 4]>(sh_raw);                    // [16][128]
    float (*part)[R_BLOCK][O_BLK] =
        reinterpret_cast<float(*)[R_BLOCK][O_BLK]>(sh_raw);                // [4][16][256]

    const int lane  = threadIdx.x;                                      // 0..63
    const int y     = __builtin_amdgcn_readfirstlane((int)threadIdx.y); // 0..7, wave-uniform
    const int chunk = y & 3;                   // i-chunk
    const int half  = y >> 2;                  // row half
    const int tid   = y * LANES + lane;        // 0..511
    const int obase = blockIdx.x * O_BLK;
    const int b0    = blockIdx.y * R_BLOCK;
    const int rbase = half * R_HALF;
    const int qbase = chunk * QPC;             // first i-quad of this chunk

    // Lane-varying base + uniform offsets -> saddr-form global loads.
    const float4* abp = ab4 + obase + lane;

    // Prime the 2-deep ab pipeline: set A = quad qbase, set B = qbase+1.
    // Quad q needs ab pair-rows 2q (i=4q..4q+1) and 2q+1 (i=4q+2..4q+3).
    float4 cA0[T_O], cA1[T_O], cB0[T_O], cB1[T_O];
#pragma unroll
    for (int j = 0; j < T_O; ++j) {
        cA0[j] = abp[(size_t)(2 * qbase + 0) * O_DIM + 64 * j];
        cA1[j] = abp[(size_t)(2 * qbase + 1) * O_DIM + 64 * j];
        cB0[j] = abp[(size_t)(2 * qbase + 2) * O_DIM + 64 * j];
        cB1[j] = abp[(size_t)(2 * qbase + 3) * O_DIM + 64 * j];
    }

    // Stage x tile: rows b0..b0+15 are contiguous in global (16 x 2 KB), so
    // the whole 32 KB tile is a flat coalesced copy: 2048 float4 / 512 thr.
    {
        const float4* xsrc = (const float4*)x + (size_t)b0 * (I_DIM / 4);
        float4* xdst = (float4*)sh_raw;
#pragma unroll
        for (int p = 0; p < 4; ++p)
            xdst[p * 512 + tid] = xsrc[p * 512 + tid];
    }
    __syncthreads();

    float acc[R_HALF][T_O];
#pragma unroll
    for (int r = 0; r < R_HALF; ++r)
#pragma unroll
        for (int j = 0; j < T_O; ++j) acc[r][j] = 1.0f;

    for (int qq = 0; qq < QPC; qq += 2) {
        // ---- body A: quad qbase+qq ----
        {
            const int q = qbase + qq;
#pragma unroll
            for (int r = 0; r < R_HALF; ++r) {
                float4 xv = xs4[rbase + r][q];   // broadcast ds_read_b128
#pragma unroll
                for (int j = 0; j < T_O; ++j) {
                    float f0 = fmaf(cA0[j].z, xv.x, cA0[j].x);
                    float f1 = fmaf(cA0[j].w, xv.y, cA0[j].y);
                    float f2 = fmaf(cA1[j].z, xv.z, cA1[j].x);
                    float f3 = fmaf(cA1[j].w, xv.w, cA1[j].y);
                    acc[r][j] *= (f0 * f2) * (f1 * f3);
                }
            }
            // Refill set A for quad q+2 (consumed one full body later).
            // Final iters overrun ab4 by <=4 rows (32 KB) -> inside ws slack.
#pragma unroll
            for (int j = 0; j < T_O; ++j) {
                cA0[j] = abp[(size_t)(2 * q + 4) * O_DIM + 64 * j];
                cA1[j] = abp[(size_t)(2 * q + 5) * O_DIM + 64 * j];
            }
        }
        // ---- body B: quad qbase+qq+1 ----
        {
            const int q = qbase + qq + 1;
#pragma unroll
            for (int r = 0; r < R_HALF; ++r) {
                float4 xv = xs4[rbase + r][q];
#pragma unroll
                for (int j = 0; j < T_O; ++j) {
                    float f0 = fmaf(cB0[j].z, xv.x, cB0[j].x);
                    float f1 = fmaf(cB0[j].w, xv.y, cB0[j].y);
                    float f2 = fmaf(cB1[j].z, xv.z, cB1[j].x);
                    float f3 = fmaf(cB1[j].w, xv.w, cB1[j].y);
                    acc[r][j] *= (f0 * f2) * (f1 * f3);
                }
            }
#pragma unroll
            for (int j = 0; j < T_O; ++j) {
                cB0[j] = abp[(size_t)(2 * q + 4) * O_DIM + 64 * j];
                cB1[j] = abp[(size_t)(2 * q + 5) * O_DIM + 64 * j];
            }
        }
    }

    // ---- combine the 4 i-chunk partials per (row, o) ----
    // part overlays xs4: barrier ensures all waves finished reading x.
    __syncthreads();
#pragma unroll
    for (int r = 0; r < R_HALF; ++r)
#pragma unroll
        for (int j = 0; j < T_O; ++j)
            part[chunk][rbase + r][64 * j + lane] = acc[r][j];
    __syncthreads();
    // Fold: 16 rows x 256 cols = 4096 outputs / 512 threads = 8 each,
    // lane-consecutive columns -> coalesced stores.
#pragma unroll
    for (int p = 0; p < 8; ++p) {
        int idx = p * 512 + tid;                  // 0..4095
        int r = idx >> 8;                         // 0..15
        int c = idx & (O_BLK - 1);                // 0..255
        float v = part[0][r][c] * part[1][r][c]
                * part[2][r][c] * part[3][r][c];
        out[(size_t)(b0 + r) * O_DIM + obase + c] = v;
    }
}

extern "C" void kernel_launch(void* const* d_in, const int* in_sizes, int n_in,
                              void* d_out, int out_size, void* d_ws, size_t ws_size,
                              hipStream_t stream) {
    const float* x        = (const float*)d_in[0];   // (B, I) fp32
    const float* w_logits = (const float*)d_in[1];   // (I, O) fp32
    const float* s_logits = (const float*)d_in[2];   // (I, O) fp32
    float* out = (float*)d_out;                      // (B, O) fp32
    float4* ab4 = (float4*)d_ws;                     // [0, 2MB) + prefetch slack

    // Setup: ab table only (512 blocks).
    setup_kernel<<<dim3(512), dim3(256), 0, stream>>>(w_logits, s_logits, ab4);

    // Grid (O/256, B/16) = (2, 128) = 256 blocks of (64,8)=512 threads.
    fuzzy_main<<<dim3(O_DIM / O_BLK, B_DIM / R_BLOCK), dim3(LANES, NCHUNK * NHALF), 0, stream>>>(
        x, ab4, out);
}

// Round 4
// 87.816 us; speedup vs baseline: 1.4645x; 1.0482x over previous
//
#include <hip/hip_runtime.h>
#include <math.h>

// Problem constants (from reference): B=2048, I=512, O=512
#define B_DIM 2048
#define I_DIM 512
#define O_DIM 512

constexpr int LANES   = 64;                    // threadIdx.x = one wave, spans 64 o
constexpr int T_O     = 4;                     // o's per thread
constexpr int O_BLK   = LANES * T_O;           // 256 o per block
constexpr int NCHUNK  = 8;                     // i-chunks (64 i each) — one per wave, DISJOINT ab
constexpr int R_BLOCK = 16;                    // rows per block (all rows per thread now)
constexpr int QPC     = (I_DIM / 4) / NCHUNK;  // 16 i-quads per chunk

// ---------------------------------------------------------------------------
// Setup kernel: precompute the affine ab table.
//   factor[b,i,o] = 1 - w*(1 - xnor) = a[i,o] + bcoef[i,o]*x[b,i]
//   a = 1 - w*s ; bcoef = w*(2s - 1)
// ab layout: float4 (a0,a1,b0,b1) at ab4[k*O_DIM+o], k = i/2.
// ---------------------------------------------------------------------------
__global__ __launch_bounds__(256) void setup_kernel(
    const float* __restrict__ w_logits,
    const float* __restrict__ s_logits,
    float4* __restrict__ ab4)
{
    int t  = blockIdx.x * 256 + threadIdx.x;  // 0 .. 131071
    int o  = t & (O_DIM - 1);
    int k  = t >> 9;                          // i-pair index, 0..255
    int i0 = 2 * k;

    float zw0 = w_logits[(i0 + 0) * O_DIM + o];
    float zs0 = s_logits[(i0 + 0) * O_DIM + o];
    float zw1 = w_logits[(i0 + 1) * O_DIM + o];
    float zs1 = s_logits[(i0 + 1) * O_DIM + o];

    float w0 = 1.0f / (1.0f + expf(-zw0));
    float s0 = 1.0f / (1.0f + expf(-zs0));
    float w1 = 1.0f / (1.0f + expf(-zw1));
    float s1 = 1.0f / (1.0f + expf(-zs1));

    float4 v;
    v.x = fmaf(-w0, s0, 1.0f);        // a0
    v.y = fmaf(-w1, s1, 1.0f);        // a1
    v.z = w0 * (2.0f * s0 - 1.0f);    // b0
    v.w = w1 * (2.0f * s1 - 1.0f);    // b1
    ab4[k * O_DIM + o] = v;
}

// ---------------------------------------------------------------------------
// Main product kernel. Block (64,8) = 8 waves, threadIdx.y = i-chunk (64 i).
// Each thread: 16 b-rows x 4 o x 64 i. Grid (2,128) = 256 blocks = 1/CU.
//
// R3 post-mortem: the 2-row-half structure made wave pairs read IDENTICAL ab
// slices -> 2 MB/CU through L1/L2 (~70 B/cy at full pace, over both per-CU
// ceilings); serialized L2+VALU+LDS matched the ~38us measured. This version
// gives every wave a DISJOINT 64-i chunk: ab traffic halves to 1 MB/block
// (~36 B/cy), at the cost of acc[16][4]=64 VGPRs. Total demand ~170 VGPRs --
// fits the 256-VGPR cap of __launch_bounds__(512,2) without spilling (R2's
// spill came from demand ~280 > cap).
// Per-CU model: VALU 32.8k cyc (13.7us) vs LDS 24.6k (10.2us) vs L2 ~17k.
// ---------------------------------------------------------------------------
__global__ __launch_bounds__(512, 2) void fuzzy_main(
    const float* __restrict__ x,       // (B, I) fp32
    const float4* __restrict__ ab4,
    float* __restrict__ out)
{
    // 64 KB LDS, overlaid: x-tile (32 KB) during the product loop, then the
    // 4-buffer combine region (64 KB) after a barrier.
    __shared__ __align__(16) unsigned char sh_raw[4 * R_BLOCK * O_BLK * 4];
    float4 (*xs4)[I_DIM / 4] =
        reinterpret_cast<float4(*)[I_DIM / 4]>(sh_raw);                    // [16][128]
    float (*part)[R_BLOCK][O_BLK] =
        reinterpret_cast<float(*)[R_BLOCK][O_BLK]>(sh_raw);                // [4][16][256]

    const int lane  = threadIdx.x;                                      // 0..63
    const int y     = __builtin_amdgcn_readfirstlane((int)threadIdx.y); // 0..7, wave-uniform
    const int tid   = y * LANES + lane;        // 0..511
    const int obase = blockIdx.x * O_BLK;
    const int b0    = blockIdx.y * R_BLOCK;
    const int qbase = y * QPC;                 // first i-quad of this wave's chunk

    // Lane-varying base + uniform offsets -> saddr-form global loads.
    const float4* abp = ab4 + obase + lane;

    // Prime the 2-deep ab pipeline: set A = quad qbase, set B = qbase+1.
    // Quad q needs ab pair-rows 2q (i=4q..4q+1) and 2q+1 (i=4q+2..4q+3).
    float4 cA0[T_O], cA1[T_O], cB0[T_O], cB1[T_O];
#pragma unroll
    for (int j = 0; j < T_O; ++j) {
        cA0[j] = abp[(size_t)(2 * qbase + 0) * O_DIM + 64 * j];
        cA1[j] = abp[(size_t)(2 * qbase + 1) * O_DIM + 64 * j];
        cB0[j] = abp[(size_t)(2 * qbase + 2) * O_DIM + 64 * j];
        cB1[j] = abp[(size_t)(2 * qbase + 3) * O_DIM + 64 * j];
    }

    // Stage x tile: rows b0..b0+15 are contiguous in global (16 x 2 KB), so
    // the whole 32 KB tile is a flat coalesced copy: 2048 float4 / 512 thr.
    {
        const float4* xsrc = (const float4*)x + (size_t)b0 * (I_DIM / 4);
        float4* xdst = (float4*)sh_raw;
#pragma unroll
        for (int p = 0; p < 4; ++p)
            xdst[p * 512 + tid] = xsrc[p * 512 + tid];
    }
    __syncthreads();

    float acc[R_BLOCK][T_O];
#pragma unroll
    for (int r = 0; r < R_BLOCK; ++r)
#pragma unroll
        for (int j = 0; j < T_O; ++j) acc[r][j] = 1.0f;

    for (int qq = 0; qq < QPC; qq += 2) {      // 8 iters, 2 quad-bodies each
        // ---- body A: quad qbase+qq ----
        {
            const int q = qbase + qq;
#pragma unroll
            for (int r = 0; r < R_BLOCK; ++r) {
                float4 xv = xs4[r][q];         // broadcast ds_read_b128
#pragma unroll
                for (int j = 0; j < T_O; ++j) {
                    float f0 = fmaf(cA0[j].z, xv.x, cA0[j].x);
                    float f1 = fmaf(cA0[j].w, xv.y, cA0[j].y);
                    float f2 = fmaf(cA1[j].z, xv.z, cA1[j].x);
                    float f3 = fmaf(cA1[j].w, xv.w, cA1[j].y);
                    acc[r][j] *= (f0 * f2) * (f1 * f3);
                }
            }
            // Refill set A for quad q+2 (consumed one full body later).
            // Final iters overrun ab4 by <=2 rows (16 KB) -> inside ws slack.
#pragma unroll
            for (int j = 0; j < T_O; ++j) {
                cA0[j] = abp[(size_t)(2 * q + 4) * O_DIM + 64 * j];
                cA1[j] = abp[(size_t)(2 * q + 5) * O_DIM + 64 * j];
            }
        }
        // ---- body B: quad qbase+qq+1 ----
        {
            const int q = qbase + qq + 1;
#pragma unroll
            for (int r = 0; r < R_BLOCK; ++r) {
                float4 xv = xs4[r][q];
#pragma unroll
                for (int j = 0; j < T_O; ++j) {
                    float f0 = fmaf(cB0[j].z, xv.x, cB0[j].x);
                    float f1 = fmaf(cB0[j].w, xv.y, cB0[j].y);
                    float f2 = fmaf(cB1[j].z, xv.z, cB1[j].x);
                    float f3 = fmaf(cB1[j].w, xv.w, cB1[j].y);
                    acc[r][j] *= (f0 * f2) * (f1 * f3);
                }
            }
#pragma unroll
            for (int j = 0; j < T_O; ++j) {
                cB0[j] = abp[(size_t)(2 * q + 4) * O_DIM + 64 * j];
                cB1[j] = abp[(size_t)(2 * q + 5) * O_DIM + 64 * j];
            }
        }
    }

    // ---- combine the 8 i-chunk partials per (row, o) ----
    // part overlays xs4: barrier ensures all waves finished reading x.
    __syncthreads();
    // Phase 1: chunks 0..3 write their partials into the 4 buffers.
    if (y < 4) {
#pragma unroll
        for (int r = 0; r < R_BLOCK; ++r)
#pragma unroll
            for (int j = 0; j < T_O; ++j)
                part[y][r][64 * j + lane] = acc[r][j];
    }
    __syncthreads();
    // Phase 2: chunks 4..7 multiply into buffers 0..3 (1:1, race-free).
    if (y >= 4) {
#pragma unroll
        for (int r = 0; r < R_BLOCK; ++r)
#pragma unroll
            for (int j = 0; j < T_O; ++j)
                part[y - 4][r][64 * j + lane] *= acc[r][j];
    }
    __syncthreads();
    // Phase 3: fold the 4 buffers; 4096 outputs / 512 threads = 8 each,
    // lane-consecutive columns -> coalesced stores.
#pragma unroll
    for (int p = 0; p < 8; ++p) {
        int idx = p * 512 + tid;                  // 0..4095
        int r = idx >> 8;                         // 0..15
        int c = idx & (O_BLK - 1);                // 0..255
        float v = part[0][r][c] * part[1][r][c]
                * part[2][r][c] * part[3][r][c];
        out[(size_t)(b0 + r) * O_DIM + obase + c] = v;
    }
}

extern "C" void kernel_launch(void* const* d_in, const int* in_sizes, int n_in,
                              void* d_out, int out_size, void* d_ws, size_t ws_size,
                              hipStream_t stream) {
    const float* x        = (const float*)d_in[0];   // (B, I) fp32
    const float* w_logits = (const float*)d_in[1];   // (I, O) fp32
    const float* s_logits = (const float*)d_in[2];   // (I, O) fp32
    float* out = (float*)d_out;                      // (B, O) fp32
    float4* ab4 = (float4*)d_ws;                     // [0, 2MB) + prefetch slack

    // Setup: ab table only (512 blocks).
    setup_kernel<<<dim3(512), dim3(256), 0, stream>>>(w_logits, s_logits, ab4);

    // Grid (O/256, B/16) = (2, 128) = 256 blocks of (64,8)=512 threads.
    fuzzy_main<<<dim3(O_DIM / O_BLK, B_DIM / R_BLOCK), dim3(LANES, NCHUNK), 0, stream>>>(
        x, ab4, out);
}